// Round 4
// baseline (35.742 us; speedup 1.0000x reference)
//
#include <hip/hip_runtime.h>
#include <math.h>

// YOLO-style loss, fused streaming reduction with LDS staging.
// Block = 256 threads = 256 cells. Global loads are flat float4 (fully coalesced,
// no per-cell address divergence); compute reads cells from LDS.
// pred: 16 f32/cell, compacted to 9 needed dwords (k=0..4,9..12) at stride 9 (coprime 32 -> conflict-free).
// tgt: 13 f32/cell, stored linearly at stride 13 (coprime 32 -> conflict-free).

#define EPSV 1e-6f
#define CHUNK 256
#define NSLOT 9

__global__ __launch_bounds__(256) void phobia_partial(
    const float* __restrict__ pred, const float* __restrict__ tgt,
    float* __restrict__ ws, int nchunks)
{
    __shared__ float sp[CHUNK * NSLOT];   // 9216 B
    __shared__ float st[CHUNK * 13];      // 13312 B

    const int t = threadIdx.x;
    float accA = 0.f, accB = 0.f, accC = 0.f;

    for (int chunk = blockIdx.x; chunk < nchunks; chunk += gridDim.x) {
        // ---- stage pred: 1024 float4 per chunk, coalesced ----
        const float4* pf4 = reinterpret_cast<const float4*>(pred) + (size_t)chunk * (CHUNK * 4);
        #pragma unroll
        for (int s = 0; s < 4; ++s) {
            int f = s * 256 + t;
            float4 v = pf4[f];
            int cell = f >> 2, quad = f & 3;
            float* dst = &sp[cell * NSLOT];
            if (quad == 0)      { dst[0] = v.x; dst[1] = v.y; dst[2] = v.z; dst[3] = v.w; }
            else if (quad == 1) { dst[4] = v.x; }
            else if (quad == 2) { dst[5] = v.y; dst[6] = v.z; dst[7] = v.w; }
            else                { dst[8] = v.x; }
        }
        // ---- stage tgt: 832 float4 per chunk, coalesced, linear in LDS ----
        const float4* tf4 = reinterpret_cast<const float4*>(tgt) + (size_t)chunk * (CHUNK * 13 / 4);
        float4* stf4 = reinterpret_cast<float4*>(st);
        #pragma unroll
        for (int s = 0; s < 3; ++s) stf4[s * 256 + t] = tf4[s * 256 + t];
        if (t < 64) stf4[768 + t] = tf4[768 + t];
        __syncthreads();

        // ---- compute own cell from LDS ----
        const float* pp = &sp[t * NSLOT];
        const float* tr = &st[t * 13];
        float p0 = pp[0], p1 = pp[1], p2 = pp[2], p3 = pp[3], p4 = pp[4];
        float p9 = pp[5], p10 = pp[6], p11 = pp[7], p12 = pp[8];
        float t0 = tr[0], t1 = tr[1], t2 = tr[2], t3 = tr[3], t4 = tr[4];
        float t10 = tr[10], t11 = tr[11], t12 = tr[12];

        float m = (t4 > 0.f) ? 1.f : 0.f;

        // coord
        float px = 1.f / (1.f + __expf(-p0));
        float py = 1.f / (1.f + __expf(-p1));
        float dx = px - t0;
        float dy = py - t1;
        float dw = sqrtf(fabsf(p2) + EPSV) - sqrtf(fabsf(t2) + EPSV);
        float dh = sqrtf(fabsf(p3) + EPSV) - sqrtf(fabsf(t3) + EPSV);
        float coord = dx*dx + dy*dy + dw*dw + dh*dh;

        // conf ch4
        float l1p4 = __logf(1.f + __expf(-fabsf(p4)));
        float logsig_p4 = fminf(p4, 0.f) - l1p4;
        float logsig_m4 = fminf(-p4, 0.f) - l1p4;
        float bce_obj = -(t4 * logsig_p4 + (1.f - t4) * logsig_m4);
        float bce_no4 = -logsig_m4;
        float bce_no9 = fmaxf(p9, 0.f) + __logf(1.f + __expf(-fabsf(p9)));

        // class CE (first-max argmax of one-hot, stable LSE)
        int tcls = 0; float bt = t10;
        if (t11 > bt) { bt = t11; tcls = 1; }
        if (t12 > bt) { tcls = 2; }
        float lt = (tcls == 0) ? p10 : ((tcls == 1) ? p11 : p12);
        float mx = fmaxf(p10, fmaxf(p11, p12));
        float lse = mx + __logf(__expf(p10 - mx) + __expf(p11 - mx) + __expf(p12 - mx));
        float ce = lse - lt;

        accA += m * (5.f * coord + bce_obj + ce);
        accB += (1.f - m) * (bce_no4 + bce_no9);
        accC += m;

        __syncthreads();   // LDS reused next chunk iteration
    }

    #pragma unroll
    for (int o = 32; o > 0; o >>= 1) {
        accA += __shfl_down(accA, o, 64);
        accB += __shfl_down(accB, o, 64);
        accC += __shfl_down(accC, o, 64);
    }
    __shared__ float sA[4], sB[4], sC[4];
    int wave = threadIdx.x >> 6;
    int lane = threadIdx.x & 63;
    if (lane == 0) { sA[wave] = accA; sB[wave] = accB; sC[wave] = accC; }
    __syncthreads();
    if (threadIdx.x == 0) {
        ws[blockIdx.x * 3 + 0] = sA[0] + sA[1] + sA[2] + sA[3];
        ws[blockIdx.x * 3 + 1] = sB[0] + sB[1] + sB[2] + sB[3];
        ws[blockIdx.x * 3 + 2] = sC[0] + sC[1] + sC[2] + sC[3];
    }
}

__global__ __launch_bounds__(1024) void phobia_final(
    const float* __restrict__ ws, int nblocks, float* __restrict__ out, long long cells)
{
    float a = 0.f, b = 0.f, c = 0.f;
    for (int i = threadIdx.x; i < nblocks; i += 1024) {
        a += ws[i * 3 + 0];
        b += ws[i * 3 + 1];
        c += ws[i * 3 + 2];
    }
    #pragma unroll
    for (int o = 32; o > 0; o >>= 1) {
        a += __shfl_down(a, o, 64);
        b += __shfl_down(b, o, 64);
        c += __shfl_down(c, o, 64);
    }
    __shared__ float sA[16], sB[16], sC[16];
    int wave = threadIdx.x >> 6;
    int lane = threadIdx.x & 63;
    if (lane == 0) { sA[wave] = a; sB[wave] = b; sC[wave] = c; }
    __syncthreads();
    if (threadIdx.x == 0) {
        float A = 0.f, B = 0.f, C = 0.f;
        #pragma unroll
        for (int w = 0; w < 16; ++w) { A += sA[w]; B += sB[w]; C += sC[w]; }
        float batch = (float)(cells / 169);
        float invb = 1.f / batch;
        float div_obj   = (C > 0.f) ? invb : 1.f;
        float div_noobj = (C < (float)cells) ? invb : 1.f;
        out[0] = A * div_obj + 0.5f * B * div_noobj;
    }
}

extern "C" void kernel_launch(void* const* d_in, const int* in_sizes, int n_in,
                              void* d_out, int out_size, void* d_ws, size_t ws_size,
                              hipStream_t stream) {
    const float* pred = (const float*)d_in[0];
    const float* tgt  = (const float*)d_in[1];
    float* out = (float*)d_out;
    float* ws  = (float*)d_ws;

    long long cells = (long long)in_sizes[0] / 16;   // 1384448 = 5408 * 256
    int nchunks = (int)(cells / CHUNK);              // 5408, exact

    int blocks = nchunks;
    size_t need = (size_t)blocks * 3 * sizeof(float);
    while (need > ws_size && blocks > 1) { blocks >>= 1; need = (size_t)blocks * 3 * sizeof(float); }

    phobia_partial<<<blocks, 256, 0, stream>>>(pred, tgt, ws, nchunks);
    phobia_final<<<1, 1024, 0, stream>>>(ws, blocks, out, cells);
}